// Round 3
// baseline (859.961 us; speedup 1.0000x reference)
//
#include <hip/hip_runtime.h>
#include <hip/hip_fp16.h>

// Binned grid-sample. Pixels are counting-sorted into 64x64 uv-tiles so each
// sampling block's gathers hit a ~6KB working set (L2/L1 resident) instead of
// thrashing the 16.7MB level-1 table. Binning affects performance only --
// every pixel is sampled with identical math and written to its own out slot.
//
// Layers are repacked (per call, in d_ws) to fp16 ROW-PAIR layout:
//   R[y][x] = half2( img[y][x], img[min(y+1,S-1)][x] )
// so one 8B load at (clamp(y0), clamp(x0,0,S-2)) yields the whole 2x2 quad.

#define NBINS 4096  // 64 x 64 uv tiles

// ---------------- repack (vectorized: float4 in, 4x half2 = uint4 out) -----
__global__ __launch_bounds__(256) void repack4_kernel(
    const float* __restrict__ src, __half2* __restrict__ dst, int S, int logS) {
    int t = blockIdx.x * blockDim.x + threadIdx.x;
    int idx = t * 4;
    int N = S << logS;
    if (idx >= N) return;
    int y = idx >> logS;
    float4 a = *(const float4*)(src + idx);
    float4 b = *(const float4*)(src + ((y < S - 1) ? idx + S : idx));
    __half2 q[4];
    q[0] = __halves2half2(__float2half(a.x), __float2half(b.x));
    q[1] = __halves2half2(__float2half(a.y), __float2half(b.y));
    q[2] = __halves2half2(__float2half(a.z), __float2half(b.z));
    q[3] = __halves2half2(__float2half(a.w), __float2half(b.w));
    *(uint4*)(dst + idx) = *(const uint4*)q;
}

// ---------------- binning ---------------------------------------------------
__device__ __forceinline__ int bin_key(float2 p) {
    int kx = min(63, max(0, (int)(p.x * 64.0f)));
    int ky = min(63, max(0, (int)(p.y * 64.0f)));
    return (ky << 6) | kx;
}

__global__ void zero_hist(unsigned* __restrict__ hist) {
    int i = blockIdx.x * blockDim.x + threadIdx.x;
    if (i < NBINS) hist[i] = 0;
}

__global__ __launch_bounds__(256) void hist_kernel(
    const float2* __restrict__ uv, unsigned* __restrict__ hist, int n) {
    __shared__ unsigned h[NBINS];
    for (int j = threadIdx.x; j < NBINS; j += 256) h[j] = 0;
    __syncthreads();
    int stride = gridDim.x * 256;
    for (int i = blockIdx.x * 256 + threadIdx.x; i < n; i += stride)
        atomicAdd(&h[bin_key(uv[i])], 1u);
    __syncthreads();
    for (int j = threadIdx.x; j < NBINS; j += 256) {
        unsigned c = h[j];
        if (c) atomicAdd(&hist[j], c);
    }
}

__global__ __launch_bounds__(1024) void scan_kernel(
    const unsigned* __restrict__ hist, unsigned* __restrict__ start,
    unsigned* __restrict__ cursor) {
    __shared__ unsigned s[1024];
    int t = threadIdx.x;
    unsigned v[4], sum = 0;
    for (int j = 0; j < 4; j++) { v[j] = hist[t * 4 + j]; sum += v[j]; }
    s[t] = sum;
    __syncthreads();
    for (int off = 1; off < 1024; off <<= 1) {
        unsigned x = (t >= off) ? s[t - off] : 0;
        __syncthreads();
        s[t] += x;
        __syncthreads();
    }
    unsigned run = (t > 0) ? s[t - 1] : 0;
    for (int j = 0; j < 4; j++) {
        start[t * 4 + j] = run;
        cursor[t * 4 + j] = run;
        run += v[j];
    }
    if (t == 1023) start[NBINS] = run;
}

__global__ __launch_bounds__(256) void scatter_kernel(
    const float2* __restrict__ uv, unsigned* __restrict__ cursor,
    float2* __restrict__ suv, unsigned* __restrict__ sidx, int n) {
    int stride = gridDim.x * 256;
    for (int i = blockIdx.x * 256 + threadIdx.x; i < n; i += stride) {
        float2 p = uv[i];
        unsigned pos = atomicAdd(&cursor[bin_key(p)], 1u);
        suv[pos] = p;
        sidx[pos] = (unsigned)i;
    }
}

// ---------------- sampling core (same math as R1, passed at absmax 0.031) --
__device__ __forceinline__ float sample_level(const __half2* __restrict__ R,
                                              const int S, const float gx,
                                              const float gy) {
    const float halfS = 0.5f * (float)S;
    float x = (gx + 1.0f) * halfS - 0.5f;
    float y = (gy + 1.0f) * halfS - 0.5f;
    float xf = floorf(x), yf = floorf(y);
    float wx = x - xf, wy = y - yf;
    int x0 = (int)xf, y0 = (int)yf;

    int yc = min(max(y0, 0), S - 1);
    float wa = (y0 >= 0) ? (1.0f - wy) : wy;
    if (y0 < -1 || y0 >= S) wa = 0.0f;
    float wb = (y0 >= 0 && y0 < S - 1) ? wy : 0.0f;

    int xb = min(max(x0, 0), S - 2);
    bool xin = (x0 >= 0) && (x0 <= S - 2);
    float wxa = xin ? (1.0f - wx) : ((x0 == -1) ? wx : 0.0f);
    float wxb = xin ? wx : ((x0 == S - 1) ? (1.0f - wx) : 0.0f);

    uint2 q;
    __builtin_memcpy(&q, (const char*)(R + (size_t)yc * (size_t)S + xb), 8);
    __half2 ca = *(const __half2*)&q.x;
    __half2 cb = *(const __half2*)&q.y;
    float2 fa = __half22float2(ca);
    float2 fb = __half22float2(cb);
    float cola = fmaf(wa, fa.x, wb * fa.y);
    float colb = fmaf(wa, fb.x, wb * fb.y);
    return fmaf(wxa, cola, wxb * colb);
}

__global__ __launch_bounds__(256) void sample_sorted_kernel(
    const float2* __restrict__ suv, const unsigned* __restrict__ sidx,
    const unsigned* __restrict__ start, const __half2* __restrict__ r1,
    const __half2* __restrict__ r2, const __half2* __restrict__ r3,
    const __half2* __restrict__ r4, float* __restrict__ out) {
    unsigned s = start[blockIdx.x];
    unsigned e = start[blockIdx.x + 1];
    for (unsigned k = s + threadIdx.x; k < e; k += 256) {
        float2 p = suv[k];
        float gx = p.x * 2.0f - 1.0f;
        float gy = p.y * 2.0f - 1.0f;
        float acc = sample_level(r1, 2048, gx, gy);
        acc += sample_level(r2, 1024, gx, gy);
        acc += sample_level(r3, 512, gx, gy);
        acc += sample_level(r4, 256, gx, gy);
        out[sidx[k]] = acc;
    }
}

// ---------------- fallbacks -------------------------------------------------
__global__ __launch_bounds__(256) void lappyr_sample_kernel(
    const float2* __restrict__ uv, const __half2* __restrict__ r1,
    const __half2* __restrict__ r2, const __half2* __restrict__ r3,
    const __half2* __restrict__ r4, float* __restrict__ out, int n) {
    int i = blockIdx.x * blockDim.x + threadIdx.x;
    if (i >= n) return;
    float2 p = uv[i];
    float gx = p.x * 2.0f - 1.0f;
    float gy = p.y * 2.0f - 1.0f;
    float acc = sample_level(r1, 2048, gx, gy);
    acc += sample_level(r2, 1024, gx, gy);
    acc += sample_level(r3, 512, gx, gy);
    acc += sample_level(r4, 256, gx, gy);
    out[i] = acc;
}

__device__ __forceinline__ float bilin_f32(const float* __restrict__ img,
                                           const int S, const float gx,
                                           const float gy) {
    const float halfS = 0.5f * (float)S;
    float x = (gx + 1.0f) * halfS - 0.5f;
    float y = (gy + 1.0f) * halfS - 0.5f;
    float xf = floorf(x), yf = floorf(y);
    float wx = x - xf, wy = y - yf;
    int x0 = (int)xf, y0 = (int)yf, x1 = x0 + 1, y1 = y0 + 1;
    float ex0 = (x0 >= 0 && x0 < S) ? (1.0f - wx) : 0.0f;
    float ex1 = (x1 >= 0 && x1 < S) ? wx : 0.0f;
    float ey0 = (y0 >= 0 && y0 < S) ? (1.0f - wy) : 0.0f;
    float ey1 = (y1 >= 0 && y1 < S) ? wy : 0.0f;
    int xc0 = min(max(x0, 0), S - 1), xc1 = min(max(x1, 0), S - 1);
    int yc0 = min(max(y0, 0), S - 1), yc1 = min(max(y1, 0), S - 1);
    const float* r0 = img + (size_t)yc0 * S;
    const float* r1 = img + (size_t)yc1 * S;
    return ey0 * fmaf(ex0, r0[xc0], ex1 * r0[xc1]) +
           ey1 * fmaf(ex0, r1[xc0], ex1 * r1[xc1]);
}

__global__ __launch_bounds__(256) void lappyr_f32_kernel(
    const float2* __restrict__ uv, const float* __restrict__ l1,
    const float* __restrict__ l2, const float* __restrict__ l3,
    const float* __restrict__ l4, float* __restrict__ out, int n) {
    int i = blockIdx.x * blockDim.x + threadIdx.x;
    if (i >= n) return;
    float2 p = uv[i];
    float gx = p.x * 2.0f - 1.0f;
    float gy = p.y * 2.0f - 1.0f;
    float acc = bilin_f32(l1, 2048, gx, gy);
    acc += bilin_f32(l2, 1024, gx, gy);
    acc += bilin_f32(l3, 512, gx, gy);
    acc += bilin_f32(l4, 256, gx, gy);
    out[i] = acc;
}

// ---------------- launch ----------------------------------------------------
extern "C" void kernel_launch(void* const* d_in, const int* in_sizes, int n_in,
                              void* d_out, int out_size, void* d_ws, size_t ws_size,
                              hipStream_t stream) {
    const float2* uv = (const float2*)d_in[0];
    const float* l1 = (const float*)d_in[1];
    const float* l2 = (const float*)d_in[2];
    const float* l3 = (const float*)d_in[3];
    const float* l4 = (const float*)d_in[4];
    float* out = (float*)d_out;
    int n = out_size;  // 8*1024*1024

    const size_t n1 = 2048u * 2048u, n2 = 1024u * 1024u, n3 = 512u * 512u,
                 n4 = 256u * 256u;
    const size_t repack_bytes = (n1 + n2 + n3 + n4) * 4;  // half2 tables
    const size_t ctrl_bytes = 65536;                      // hist+cursor+start
    const size_t need_sort =
        ctrl_bytes + repack_bytes + (size_t)n * 8 + (size_t)n * 4;

    if (ws_size >= need_sort) {
        char* base = (char*)d_ws;
        unsigned* hist = (unsigned*)base;                 // 16KB
        unsigned* cursor = (unsigned*)(base + 16384);     // 16KB
        unsigned* start = (unsigned*)(base + 32768);      // (NBINS+1)*4
        __half2* r1 = (__half2*)(base + ctrl_bytes);
        __half2* r2 = r1 + n1;
        __half2* r3 = r2 + n2;
        __half2* r4 = r3 + n3;
        float2* suv = (float2*)(base + ctrl_bytes + repack_bytes);
        unsigned* sidx = (unsigned*)(suv + n);

        repack4_kernel<<<(int)(n1 / 4 / 256), 256, 0, stream>>>(l1, r1, 2048, 11);
        repack4_kernel<<<(int)(n2 / 4 / 256), 256, 0, stream>>>(l2, r2, 1024, 10);
        repack4_kernel<<<(int)(n3 / 4 / 256), 256, 0, stream>>>(l3, r3, 512, 9);
        repack4_kernel<<<(int)(n4 / 4 / 256), 256, 0, stream>>>(l4, r4, 256, 8);
        zero_hist<<<NBINS / 256, 256, 0, stream>>>(hist);
        hist_kernel<<<1024, 256, 0, stream>>>(uv, hist, n);
        scan_kernel<<<1, 1024, 0, stream>>>(hist, start, cursor);
        scatter_kernel<<<2048, 256, 0, stream>>>(uv, cursor, suv, sidx, n);
        sample_sorted_kernel<<<NBINS, 256, 0, stream>>>(suv, sidx, start, r1, r2,
                                                        r3, r4, out);
    } else if (ws_size >= repack_bytes) {
        __half2* r1 = (__half2*)d_ws;
        __half2* r2 = r1 + n1;
        __half2* r3 = r2 + n2;
        __half2* r4 = r3 + n3;
        repack4_kernel<<<(int)(n1 / 4 / 256), 256, 0, stream>>>(l1, r1, 2048, 11);
        repack4_kernel<<<(int)(n2 / 4 / 256), 256, 0, stream>>>(l2, r2, 1024, 10);
        repack4_kernel<<<(int)(n3 / 4 / 256), 256, 0, stream>>>(l3, r3, 512, 9);
        repack4_kernel<<<(int)(n4 / 4 / 256), 256, 0, stream>>>(l4, r4, 256, 8);
        lappyr_sample_kernel<<<(n + 255) / 256, 256, 0, stream>>>(uv, r1, r2, r3,
                                                                  r4, out, n);
    } else {
        lappyr_f32_kernel<<<(n + 255) / 256, 256, 0, stream>>>(uv, l1, l2, l3, l4,
                                                               out, n);
    }
}

// Round 4
// 609.282 us; speedup vs baseline: 1.4114x; 1.4114x over previous
//
#include <hip/hip_runtime.h>
#include <hip/hip_fp16.h>

// Binned grid-sample, round 3: counting sort with NO global atomics.
//   A: per-block LDS histogram of 2048 uv-tile bins -> aux[block][bin]
//   B1: per-bin exclusive scan across blocks (in-place) + bin totals
//   B2: exclusive scan of totals -> start[bin] (start[NBINS] = n)
//   C: re-read chunk, LDS cursors = start[bin]+aux[block][bin], LDS-atomic
//      rank, write (uv, idx) records. Runs of ~16 px per (block,bin) merge
//      in L2 -> write traffic near payload, no cross-XCD cursor ping-pong.
//   Sample: one bin per block-pair, gathers hit L2 (~8 KB working set/bin).
// Layers repacked per call to fp16 row-pair layout (one 8B load = 2x2 quad).

#define NBINS 2048   // 64 x 32 uv tiles
#define NBLK 256     // sort blocks
#define SUB 2        // sample sub-blocks per bin

__device__ __forceinline__ int bin_key(float2 p) {
    int kx = min(63, max(0, (int)(p.x * 64.0f)));
    int ky = min(31, max(0, (int)(p.y * 32.0f)));
    return (ky << 6) | kx;
}

// ---------------- repack (float4 in, 4x half2 = uint4 out) ------------------
__global__ __launch_bounds__(256) void repack4_kernel(
    const float* __restrict__ src, __half2* __restrict__ dst, int S, int logS) {
    int t = blockIdx.x * blockDim.x + threadIdx.x;
    int idx = t * 4;
    int N = S << logS;
    if (idx >= N) return;
    int y = idx >> logS;
    float4 a = *(const float4*)(src + idx);
    float4 b = *(const float4*)(src + ((y < S - 1) ? idx + S : idx));
    __half2 q[4];
    q[0] = __halves2half2(__float2half(a.x), __float2half(b.x));
    q[1] = __halves2half2(__float2half(a.y), __float2half(b.y));
    q[2] = __halves2half2(__float2half(a.z), __float2half(b.z));
    q[3] = __halves2half2(__float2half(a.w), __float2half(b.w));
    *(uint4*)(dst + idx) = *(const uint4*)q;
}

// ---------------- sort passes ----------------------------------------------
__global__ __launch_bounds__(256) void histA_kernel(
    const float2* __restrict__ uv, unsigned* __restrict__ aux, int n, int chunk) {
    __shared__ unsigned h[NBINS];
    for (int j = threadIdx.x; j < NBINS; j += 256) h[j] = 0;
    __syncthreads();
    int base = blockIdx.x * chunk;
    int end = min(n, base + chunk);
    for (int i = base + threadIdx.x; i < end; i += 256)
        atomicAdd(&h[bin_key(uv[i])], 1u);
    __syncthreads();
    for (int j = threadIdx.x; j < NBINS; j += 256)
        aux[blockIdx.x * NBINS + j] = h[j];
}

__global__ __launch_bounds__(256) void colscan_kernel(
    unsigned* __restrict__ aux, unsigned* __restrict__ total, int nblk) {
    int bin = blockIdx.x * 256 + threadIdx.x;  // grid = NBINS/256
    unsigned run = 0;
    for (int b = 0; b < nblk; b++) {
        unsigned c = aux[b * NBINS + bin];
        aux[b * NBINS + bin] = run;
        run += c;
    }
    total[bin] = run;
}

__global__ __launch_bounds__(512) void binscan_kernel(
    const unsigned* __restrict__ total, unsigned* __restrict__ start) {
    __shared__ unsigned s[512];
    int t = threadIdx.x;
    unsigned v[4], sum = 0;
    for (int j = 0; j < 4; j++) { v[j] = total[t * 4 + j]; sum += v[j]; }
    s[t] = sum;
    __syncthreads();
    for (int off = 1; off < 512; off <<= 1) {
        unsigned x = (t >= off) ? s[t - off] : 0;
        __syncthreads();
        s[t] += x;
        __syncthreads();
    }
    unsigned run = (t > 0) ? s[t - 1] : 0;
    for (int j = 0; j < 4; j++) { start[t * 4 + j] = run; run += v[j]; }
    if (t == 511) start[NBINS] = run;
}

__global__ __launch_bounds__(256) void scatterC_kernel(
    const float2* __restrict__ uv, const unsigned* __restrict__ aux,
    const unsigned* __restrict__ start, float2* __restrict__ suv,
    unsigned* __restrict__ sidx, int n, int chunk) {
    __shared__ unsigned cur[NBINS];
    for (int j = threadIdx.x; j < NBINS; j += 256)
        cur[j] = start[j] + aux[blockIdx.x * NBINS + j];
    __syncthreads();
    int base = blockIdx.x * chunk;
    int end = min(n, base + chunk);
    for (int i = base + threadIdx.x; i < end; i += 256) {
        float2 p = uv[i];
        unsigned pos = atomicAdd(&cur[bin_key(p)], 1u);
        suv[pos] = p;
        sidx[pos] = (unsigned)i;
    }
}

// ---------------- sampling core (validated: absmax 0.031) -------------------
__device__ __forceinline__ float sample_level(const __half2* __restrict__ R,
                                              const int S, const float gx,
                                              const float gy) {
    const float halfS = 0.5f * (float)S;
    float x = (gx + 1.0f) * halfS - 0.5f;
    float y = (gy + 1.0f) * halfS - 0.5f;
    float xf = floorf(x), yf = floorf(y);
    float wx = x - xf, wy = y - yf;
    int x0 = (int)xf, y0 = (int)yf;

    int yc = min(max(y0, 0), S - 1);
    float wa = (y0 >= 0) ? (1.0f - wy) : wy;
    if (y0 < -1 || y0 >= S) wa = 0.0f;
    float wb = (y0 >= 0 && y0 < S - 1) ? wy : 0.0f;

    int xb = min(max(x0, 0), S - 2);
    bool xin = (x0 >= 0) && (x0 <= S - 2);
    float wxa = xin ? (1.0f - wx) : ((x0 == -1) ? wx : 0.0f);
    float wxb = xin ? wx : ((x0 == S - 1) ? (1.0f - wx) : 0.0f);

    uint2 q;
    __builtin_memcpy(&q, (const char*)(R + (size_t)yc * (size_t)S + xb), 8);
    __half2 ca = *(const __half2*)&q.x;
    __half2 cb = *(const __half2*)&q.y;
    float2 fa = __half22float2(ca);
    float2 fb = __half22float2(cb);
    float cola = fmaf(wa, fa.x, wb * fa.y);
    float colb = fmaf(wa, fb.x, wb * fb.y);
    return fmaf(wxa, cola, wxb * colb);
}

__global__ __launch_bounds__(256) void sample_sorted_kernel(
    const float2* __restrict__ suv, const unsigned* __restrict__ sidx,
    const unsigned* __restrict__ start, const __half2* __restrict__ r1,
    const __half2* __restrict__ r2, const __half2* __restrict__ r3,
    const __half2* __restrict__ r4, float* __restrict__ out) {
    int bin = blockIdx.x & (NBINS - 1);
    int sub = blockIdx.x >> 11;  // SUB=2
    unsigned s0 = start[bin], e = start[bin + 1];
    unsigned len = e - s0;
    unsigned s = s0 + (len * (unsigned)sub) / SUB;
    unsigned e2 = s0 + (len * (unsigned)(sub + 1)) / SUB;
    for (unsigned k = s + threadIdx.x; k < e2; k += 256) {
        float2 p = suv[k];
        float gx = p.x * 2.0f - 1.0f;
        float gy = p.y * 2.0f - 1.0f;
        float acc = sample_level(r1, 2048, gx, gy);
        acc += sample_level(r2, 1024, gx, gy);
        acc += sample_level(r3, 512, gx, gy);
        acc += sample_level(r4, 256, gx, gy);
        out[sidx[k]] = acc;
    }
}

// ---------------- fallbacks -------------------------------------------------
__global__ __launch_bounds__(256) void lappyr_sample_kernel(
    const float2* __restrict__ uv, const __half2* __restrict__ r1,
    const __half2* __restrict__ r2, const __half2* __restrict__ r3,
    const __half2* __restrict__ r4, float* __restrict__ out, int n) {
    int i = blockIdx.x * blockDim.x + threadIdx.x;
    if (i >= n) return;
    float2 p = uv[i];
    float gx = p.x * 2.0f - 1.0f;
    float gy = p.y * 2.0f - 1.0f;
    float acc = sample_level(r1, 2048, gx, gy);
    acc += sample_level(r2, 1024, gx, gy);
    acc += sample_level(r3, 512, gx, gy);
    acc += sample_level(r4, 256, gx, gy);
    out[i] = acc;
}

__device__ __forceinline__ float bilin_f32(const float* __restrict__ img,
                                           const int S, const float gx,
                                           const float gy) {
    const float halfS = 0.5f * (float)S;
    float x = (gx + 1.0f) * halfS - 0.5f;
    float y = (gy + 1.0f) * halfS - 0.5f;
    float xf = floorf(x), yf = floorf(y);
    float wx = x - xf, wy = y - yf;
    int x0 = (int)xf, y0 = (int)yf, x1 = x0 + 1, y1 = y0 + 1;
    float ex0 = (x0 >= 0 && x0 < S) ? (1.0f - wx) : 0.0f;
    float ex1 = (x1 >= 0 && x1 < S) ? wx : 0.0f;
    float ey0 = (y0 >= 0 && y0 < S) ? (1.0f - wy) : 0.0f;
    float ey1 = (y1 >= 0 && y1 < S) ? wy : 0.0f;
    int xc0 = min(max(x0, 0), S - 1), xc1 = min(max(x1, 0), S - 1);
    int yc0 = min(max(y0, 0), S - 1), yc1 = min(max(y1, 0), S - 1);
    const float* r0 = img + (size_t)yc0 * S;
    const float* r1 = img + (size_t)yc1 * S;
    return ey0 * fmaf(ex0, r0[xc0], ex1 * r0[xc1]) +
           ey1 * fmaf(ex0, r1[xc0], ex1 * r1[xc1]);
}

__global__ __launch_bounds__(256) void lappyr_f32_kernel(
    const float2* __restrict__ uv, const float* __restrict__ l1,
    const float* __restrict__ l2, const float* __restrict__ l3,
    const float* __restrict__ l4, float* __restrict__ out, int n) {
    int i = blockIdx.x * blockDim.x + threadIdx.x;
    if (i >= n) return;
    float2 p = uv[i];
    float gx = p.x * 2.0f - 1.0f;
    float gy = p.y * 2.0f - 1.0f;
    float acc = bilin_f32(l1, 2048, gx, gy);
    acc += bilin_f32(l2, 1024, gx, gy);
    acc += bilin_f32(l3, 512, gx, gy);
    acc += bilin_f32(l4, 256, gx, gy);
    out[i] = acc;
}

// ---------------- launch ----------------------------------------------------
extern "C" void kernel_launch(void* const* d_in, const int* in_sizes, int n_in,
                              void* d_out, int out_size, void* d_ws, size_t ws_size,
                              hipStream_t stream) {
    const float2* uv = (const float2*)d_in[0];
    const float* l1 = (const float*)d_in[1];
    const float* l2 = (const float*)d_in[2];
    const float* l3 = (const float*)d_in[3];
    const float* l4 = (const float*)d_in[4];
    float* out = (float*)d_out;
    int n = out_size;  // 8*1024*1024

    const size_t n1 = 2048u * 2048u, n2 = 1024u * 1024u, n3 = 512u * 512u,
                 n4 = 256u * 256u;
    const size_t repack_bytes = (n1 + n2 + n3 + n4) * 4;       // 21.25 MiB
    const size_t aux_bytes = (size_t)NBLK * NBINS * 4;         // 2 MiB
    const size_t ctrl_bytes = aux_bytes + 16384 + 16384;       // aux,total,start
    const size_t need_sort =
        repack_bytes + ctrl_bytes + (size_t)n * 8 + (size_t)n * 4;

    if (ws_size >= need_sort) {
        char* base = (char*)d_ws;
        __half2* r1 = (__half2*)base;
        __half2* r2 = r1 + n1;
        __half2* r3 = r2 + n2;
        __half2* r4 = r3 + n3;
        unsigned* aux = (unsigned*)(base + repack_bytes);
        unsigned* total = (unsigned*)(base + repack_bytes + aux_bytes);
        unsigned* start = (unsigned*)(base + repack_bytes + aux_bytes + 16384);
        float2* suv = (float2*)(base + repack_bytes + ctrl_bytes);
        unsigned* sidx = (unsigned*)(suv + n);

        // chunk: per-sort-block pixel count, multiple of 256
        int chunk = (int)(((size_t)n + NBLK - 1) / NBLK);
        chunk = (chunk + 255) & ~255;

        repack4_kernel<<<(int)(n1 / 4 / 256), 256, 0, stream>>>(l1, r1, 2048, 11);
        repack4_kernel<<<(int)(n2 / 4 / 256), 256, 0, stream>>>(l2, r2, 1024, 10);
        repack4_kernel<<<(int)(n3 / 4 / 256), 256, 0, stream>>>(l3, r3, 512, 9);
        repack4_kernel<<<(int)(n4 / 4 / 256), 256, 0, stream>>>(l4, r4, 256, 8);
        histA_kernel<<<NBLK, 256, 0, stream>>>(uv, aux, n, chunk);
        colscan_kernel<<<NBINS / 256, 256, 0, stream>>>(aux, total, NBLK);
        binscan_kernel<<<1, 512, 0, stream>>>(total, start);
        scatterC_kernel<<<NBLK, 256, 0, stream>>>(uv, aux, start, suv, sidx, n,
                                                  chunk);
        sample_sorted_kernel<<<NBINS * SUB, 256, 0, stream>>>(suv, sidx, start,
                                                              r1, r2, r3, r4, out);
    } else if (ws_size >= repack_bytes) {
        __half2* r1 = (__half2*)d_ws;
        __half2* r2 = r1 + n1;
        __half2* r3 = r2 + n2;
        __half2* r4 = r3 + n3;
        repack4_kernel<<<(int)(n1 / 4 / 256), 256, 0, stream>>>(l1, r1, 2048, 11);
        repack4_kernel<<<(int)(n2 / 4 / 256), 256, 0, stream>>>(l2, r2, 1024, 10);
        repack4_kernel<<<(int)(n3 / 4 / 256), 256, 0, stream>>>(l3, r3, 512, 9);
        repack4_kernel<<<(int)(n4 / 4 / 256), 256, 0, stream>>>(l4, r4, 256, 8);
        lappyr_sample_kernel<<<(n + 255) / 256, 256, 0, stream>>>(uv, r1, r2, r3,
                                                                  r4, out, n);
    } else {
        lappyr_f32_kernel<<<(n + 255) / 256, 256, 0, stream>>>(uv, l1, l2, l3, l4,
                                                               out, n);
    }
}

// Round 6
// 487.566 us; speedup vs baseline: 1.7638x; 1.2496x over previous
//
#include <hip/hip_runtime.h>
#include <hip/hip_fp16.h>

// Sorted grid-sample, round 5. Key structural fact: scatter block g handles
// input chunk g == output segment g, and counting sort makes each block's
// deposits to a bin contiguous. So aux1[bin][g] (after colscan) is EXACTLY
// the offset of segment g's run inside bin -- per-(bin,segment) runs are
// contiguous and analytically addressable. No cells/capacity (R4's drop bug).
//  A  repack layers -> fp16 row-pair tables (one 8B load = 2x2 quad)
//  B  hist1: per-block LDS histogram -> aux1[bin][blk] (transposed)
//  C1 colscan: per-bin exclusive scan across blocks (1 wave/bin, shfl scan)
//  C2 binscan: scan bin totals -> start[bin]
//  D  scatter1: LDS cursors, write (suv, sidx) sorted records
//  E  sample sorted records linearly; write rec[pos] = (lo14<<16 | fp16 val),
//     fully coalesced
//  F  per-segment: gather the 512 per-bin runs -> 64KB LDS -> float4 out

#define NBINS 512   // 32 x 16 uv tiles
#define NBLK  512   // sort blocks == output segments
#define CHUNK 16384 // n / NBLK == SEGSZ
#define SEGSZ 16384
#define SBLK  2048  // sample blocks
#define SCHUNK 4096 // records per sample block

__device__ __forceinline__ int bin_key(float2 p) {
    int kx = min(31, max(0, (int)(p.x * 32.0f)));
    int ky = min(15, max(0, (int)(p.y * 16.0f)));
    return (ky << 5) | kx;
}

// ---------------- A: repack (float4 in, 4x half2 = uint4 out) ---------------
__global__ __launch_bounds__(256) void repack4_kernel(
    const float* __restrict__ src, __half2* __restrict__ dst, int S, int logS) {
    int t = blockIdx.x * blockDim.x + threadIdx.x;
    int idx = t * 4;
    int N = S << logS;
    if (idx >= N) return;
    int y = idx >> logS;
    float4 a = *(const float4*)(src + idx);
    float4 b = *(const float4*)(src + ((y < S - 1) ? idx + S : idx));
    __half2 q[4];
    q[0] = __halves2half2(__float2half(a.x), __float2half(b.x));
    q[1] = __halves2half2(__float2half(a.y), __float2half(b.y));
    q[2] = __halves2half2(__float2half(a.z), __float2half(b.z));
    q[3] = __halves2half2(__float2half(a.w), __float2half(b.w));
    *(uint4*)(dst + idx) = *(const uint4*)q;
}

// ---------------- B: histogram ---------------------------------------------
__global__ __launch_bounds__(256) void hist1_kernel(
    const float2* __restrict__ uv, unsigned* __restrict__ aux1) {
    __shared__ unsigned h[NBINS];
    for (int j = threadIdx.x; j < NBINS; j += 256) h[j] = 0;
    __syncthreads();
    int base = blockIdx.x * CHUNK;
    for (int i = base + threadIdx.x; i < base + CHUNK; i += 256)
        atomicAdd(&h[bin_key(uv[i])], 1u);
    __syncthreads();
    for (int j = threadIdx.x; j < NBINS; j += 256)
        aux1[j * NBLK + blockIdx.x] = h[j];
}

// ---------------- C1: per-bin scan across blocks (1 wave/bin) ---------------
__global__ __launch_bounds__(256) void colscan_kernel(
    unsigned* __restrict__ aux1, unsigned* __restrict__ total) {
    int bin = blockIdx.x * 4 + (threadIdx.x >> 6);  // grid = NBINS/4
    int lane = threadIdx.x & 63;
    unsigned* row = aux1 + (size_t)bin * NBLK;
    unsigned carry = 0;
    for (int c = 0; c < NBLK; c += 64) {
        unsigned v = row[c + lane];
        unsigned x = v;
        for (int off = 1; off < 64; off <<= 1) {
            unsigned u = __shfl_up(x, off, 64);
            if (lane >= off) x += u;
        }
        row[c + lane] = carry + x - v;  // exclusive
        carry += __shfl(x, 63, 64);
    }
    if (lane == 0) total[bin] = carry;
}

// ---------------- C2: scan of totals ---------------------------------------
__global__ __launch_bounds__(512) void binscan_kernel(
    const unsigned* __restrict__ total, unsigned* __restrict__ start) {
    __shared__ unsigned s[NBINS];
    int t = threadIdx.x;  // 512
    unsigned v = total[t];
    s[t] = v;
    __syncthreads();
    for (int off = 1; off < NBINS; off <<= 1) {
        unsigned x = (t >= off) ? s[t - off] : 0;
        __syncthreads();
        s[t] += x;
        __syncthreads();
    }
    start[t] = s[t] - v;  // exclusive
}

// ---------------- D: scatter records ---------------------------------------
__global__ __launch_bounds__(256) void scatter1_kernel(
    const float2* __restrict__ uv, const unsigned* __restrict__ aux1,
    const unsigned* __restrict__ start, float2* __restrict__ suv,
    unsigned* __restrict__ sidx) {
    __shared__ unsigned cur[NBINS];
    int g = blockIdx.x;
    for (int j = threadIdx.x; j < NBINS; j += 256)
        cur[j] = start[j] + aux1[j * NBLK + g];
    __syncthreads();
    int base = g * CHUNK;
    for (int i = base + threadIdx.x; i < base + CHUNK; i += 256) {
        float2 p = uv[i];
        unsigned pos = atomicAdd(&cur[bin_key(p)], 1u);
        suv[pos] = p;
        sidx[pos] = (unsigned)i;
    }
}

// ---------------- sampling core (validated: absmax 0.031) -------------------
__device__ __forceinline__ float sample_level(const __half2* __restrict__ R,
                                              const int S, const float gx,
                                              const float gy) {
    const float halfS = 0.5f * (float)S;
    float x = (gx + 1.0f) * halfS - 0.5f;
    float y = (gy + 1.0f) * halfS - 0.5f;
    float xf = floorf(x), yf = floorf(y);
    float wx = x - xf, wy = y - yf;
    int x0 = (int)xf, y0 = (int)yf;

    int yc = min(max(y0, 0), S - 1);
    float wa = (y0 >= 0) ? (1.0f - wy) : wy;
    if (y0 < -1 || y0 >= S) wa = 0.0f;
    float wb = (y0 >= 0 && y0 < S - 1) ? wy : 0.0f;

    int xb = min(max(x0, 0), S - 2);
    bool xin = (x0 >= 0) && (x0 <= S - 2);
    float wxa = xin ? (1.0f - wx) : ((x0 == -1) ? wx : 0.0f);
    float wxb = xin ? wx : ((x0 == S - 1) ? (1.0f - wx) : 0.0f);

    uint2 q;
    __builtin_memcpy(&q, (const char*)(R + (size_t)yc * (size_t)S + xb), 8);
    __half2 ca = *(const __half2*)&q.x;
    __half2 cb = *(const __half2*)&q.y;
    float2 fa = __half22float2(ca);
    float2 fb = __half22float2(cb);
    float cola = fmaf(wa, fa.x, wb * fa.y);
    float colb = fmaf(wa, fb.x, wb * fb.y);
    return fmaf(wxa, cola, wxb * colb);
}

__device__ __forceinline__ float sample_all(const __half2* r1, const __half2* r2,
                                            const __half2* r3, const __half2* r4,
                                            float2 p) {
    float gx = p.x * 2.0f - 1.0f;
    float gy = p.y * 2.0f - 1.0f;
    float acc = sample_level(r1, 2048, gx, gy);
    acc += sample_level(r2, 1024, gx, gy);
    acc += sample_level(r3, 512, gx, gy);
    acc += sample_level(r4, 256, gx, gy);
    return acc;
}

// ---------------- E: sample linearly, packed record out ---------------------
__global__ __launch_bounds__(256) void sample_lin_kernel(
    const float2* __restrict__ suv, const unsigned* __restrict__ sidx,
    const __half2* __restrict__ r1, const __half2* __restrict__ r2,
    const __half2* __restrict__ r3, const __half2* __restrict__ r4,
    unsigned* __restrict__ rec) {
    int base = blockIdx.x * SCHUNK;
    for (int k = base + threadIdx.x; k < base + SCHUNK; k += 256) {
        float2 p = suv[k];
        unsigned lo = sidx[k] & (SEGSZ - 1);
        float acc = sample_all(r1, r2, r3, r4, p);
        unsigned short hv = __half_as_ushort(__float2half(acc));
        rec[k] = (lo << 16) | (unsigned)hv;
    }
}

// ---------------- F: per-segment run-gather -> LDS -> coalesced out ---------
__global__ __launch_bounds__(256) void final_kernel(
    const unsigned* __restrict__ rec, const unsigned* __restrict__ aux1,
    const unsigned* __restrict__ start, const unsigned* __restrict__ total,
    float* __restrict__ out) {
    __shared__ float obuf[SEGSZ];  // 64 KB
    int s = blockIdx.x;
    for (int j = threadIdx.x; j < SEGSZ; j += 256) obuf[j] = 0.0f;
    __syncthreads();
    for (int k = threadIdx.x; k < NBINS; k += 256) {
        unsigned b0 = start[k] + aux1[(size_t)k * NBLK + s];
        unsigned b1 =
            start[k] + ((s < NBLK - 1) ? aux1[(size_t)k * NBLK + s + 1] : total[k]);
        for (unsigned t = b0; t < b1; ++t) {
            unsigned rv = rec[t];
            obuf[rv >> 16] =
                __half2float(__ushort_as_half((unsigned short)(rv & 0xFFFFu)));
        }
    }
    __syncthreads();
    float4* o4 = (float4*)(out + (size_t)s * SEGSZ);
    for (int j = threadIdx.x; j < SEGSZ / 4; j += 256)
        o4[j] = make_float4(obuf[4 * j], obuf[4 * j + 1], obuf[4 * j + 2],
                            obuf[4 * j + 3]);
}

// ---------------- fallbacks -------------------------------------------------
__global__ __launch_bounds__(256) void lappyr_sample_kernel(
    const float2* __restrict__ uv, const __half2* __restrict__ r1,
    const __half2* __restrict__ r2, const __half2* __restrict__ r3,
    const __half2* __restrict__ r4, float* __restrict__ out, int n) {
    int i = blockIdx.x * blockDim.x + threadIdx.x;
    if (i >= n) return;
    out[i] = sample_all(r1, r2, r3, r4, uv[i]);
}

__device__ __forceinline__ float bilin_f32(const float* __restrict__ img,
                                           const int S, const float gx,
                                           const float gy) {
    const float halfS = 0.5f * (float)S;
    float x = (gx + 1.0f) * halfS - 0.5f;
    float y = (gy + 1.0f) * halfS - 0.5f;
    float xf = floorf(x), yf = floorf(y);
    float wx = x - xf, wy = y - yf;
    int x0 = (int)xf, y0 = (int)yf, x1 = x0 + 1, y1 = y0 + 1;
    float ex0 = (x0 >= 0 && x0 < S) ? (1.0f - wx) : 0.0f;
    float ex1 = (x1 >= 0 && x1 < S) ? wx : 0.0f;
    float ey0 = (y0 >= 0 && y0 < S) ? (1.0f - wy) : 0.0f;
    float ey1 = (y1 >= 0 && y1 < S) ? wy : 0.0f;
    int xc0 = min(max(x0, 0), S - 1), xc1 = min(max(x1, 0), S - 1);
    int yc0 = min(max(y0, 0), S - 1), yc1 = min(max(y1, 0), S - 1);
    const float* r0 = img + (size_t)yc0 * S;
    const float* r1 = img + (size_t)yc1 * S;
    return ey0 * fmaf(ex0, r0[xc0], ex1 * r0[xc1]) +
           ey1 * fmaf(ex0, r1[xc0], ex1 * r1[xc1]);
}

__global__ __launch_bounds__(256) void lappyr_f32_kernel(
    const float2* __restrict__ uv, const float* __restrict__ l1,
    const float* __restrict__ l2, const float* __restrict__ l3,
    const float* __restrict__ l4, float* __restrict__ out, int n) {
    int i = blockIdx.x * blockDim.x + threadIdx.x;
    if (i >= n) return;
    float2 p = uv[i];
    float gx = p.x * 2.0f - 1.0f;
    float gy = p.y * 2.0f - 1.0f;
    float acc = bilin_f32(l1, 2048, gx, gy);
    acc += bilin_f32(l2, 1024, gx, gy);
    acc += bilin_f32(l3, 512, gx, gy);
    acc += bilin_f32(l4, 256, gx, gy);
    out[i] = acc;
}

// ---------------- launch ----------------------------------------------------
extern "C" void kernel_launch(void* const* d_in, const int* in_sizes, int n_in,
                              void* d_out, int out_size, void* d_ws, size_t ws_size,
                              hipStream_t stream) {
    const float2* uv = (const float2*)d_in[0];
    const float* l1 = (const float*)d_in[1];
    const float* l2 = (const float*)d_in[2];
    const float* l3 = (const float*)d_in[3];
    const float* l4 = (const float*)d_in[4];
    float* out = (float*)d_out;
    int n = out_size;  // 8*1024*1024 = NBLK*CHUNK = SBLK*SCHUNK

    const size_t n1 = 2048u * 2048u, n2 = 1024u * 1024u, n3 = 512u * 512u,
                 n4 = 256u * 256u;
    const size_t repack_bytes = (n1 + n2 + n3 + n4) * 4;  // 21.25 MiB
    const size_t aux1_bytes = (size_t)NBINS * NBLK * 4;   // 1 MiB
    const size_t tot_bytes = NBINS * 4, start_bytes = NBINS * 4;
    const size_t suv_bytes = (size_t)n * 8;
    const size_t sidx_bytes = (size_t)n * 4;
    const size_t rec_bytes = (size_t)n * 4;
    const size_t need = repack_bytes + aux1_bytes + tot_bytes + start_bytes +
                        suv_bytes + sidx_bytes + rec_bytes;  // ~150.3 MiB

    if (n == NBLK * CHUNK && ws_size >= need) {
        char* base = (char*)d_ws;
        __half2* r1 = (__half2*)base;
        __half2* r2 = r1 + n1;
        __half2* r3 = r2 + n2;
        __half2* r4 = r3 + n3;
        char* p = base + repack_bytes;
        unsigned* aux1 = (unsigned*)p;   p += aux1_bytes;
        unsigned* total = (unsigned*)p;  p += tot_bytes;
        unsigned* start = (unsigned*)p;  p += start_bytes;
        float2* suv = (float2*)p;        p += suv_bytes;
        unsigned* sidx = (unsigned*)p;   p += sidx_bytes;
        unsigned* rec = (unsigned*)p;

        repack4_kernel<<<(int)(n1 / 4 / 256), 256, 0, stream>>>(l1, r1, 2048, 11);
        repack4_kernel<<<(int)(n2 / 4 / 256), 256, 0, stream>>>(l2, r2, 1024, 10);
        repack4_kernel<<<(int)(n3 / 4 / 256), 256, 0, stream>>>(l3, r3, 512, 9);
        repack4_kernel<<<(int)(n4 / 4 / 256), 256, 0, stream>>>(l4, r4, 256, 8);
        hist1_kernel<<<NBLK, 256, 0, stream>>>(uv, aux1);
        colscan_kernel<<<NBINS / 4, 256, 0, stream>>>(aux1, total);
        binscan_kernel<<<1, NBINS, 0, stream>>>(total, start);
        scatter1_kernel<<<NBLK, 256, 0, stream>>>(uv, aux1, start, suv, sidx);
        sample_lin_kernel<<<SBLK, 256, 0, stream>>>(suv, sidx, r1, r2, r3, r4,
                                                    rec);
        final_kernel<<<NBLK, 256, 0, stream>>>(rec, aux1, start, total, out);
    } else if (ws_size >= repack_bytes) {
        __half2* r1 = (__half2*)d_ws;
        __half2* r2 = r1 + n1;
        __half2* r3 = r2 + n2;
        __half2* r4 = r3 + n3;
        repack4_kernel<<<(int)(n1 / 4 / 256), 256, 0, stream>>>(l1, r1, 2048, 11);
        repack4_kernel<<<(int)(n2 / 4 / 256), 256, 0, stream>>>(l2, r2, 1024, 10);
        repack4_kernel<<<(int)(n3 / 4 / 256), 256, 0, stream>>>(l3, r3, 512, 9);
        repack4_kernel<<<(int)(n4 / 4 / 256), 256, 0, stream>>>(l4, r4, 256, 8);
        lappyr_sample_kernel<<<(n + 255) / 256, 256, 0, stream>>>(uv, r1, r2, r3,
                                                                  r4, out, n);
    } else {
        lappyr_f32_kernel<<<(n + 255) / 256, 256, 0, stream>>>(uv, l1, l2, l3, l4,
                                                               out, n);
    }
}

// Round 7
// 433.530 us; speedup vs baseline: 1.9836x; 1.1246x over previous
//
#include <hip/hip_runtime.h>
#include <hip/hip_fp16.h>

// Sorted grid-sample, round 6. Single 8-byte sort record:
//   rec8 = u25 | v25<<25 | lo14<<50   (u,v fixed-point 25-bit; lo = idx&16383)
// Valid because scatter block g == output segment g (CHUNK==SEGSZ, aligned),
// and final addresses per-(bin,segment) runs analytically via aux1 (validated
// in R5). One record array => 512 live frontier lines/block (~1.6MB/XCD) so
// runs (32 recs = 4 full lines) merge in L2 before eviction.
//  A  repack layers -> fp16 row-pair tables (one 8B load = 2x2 quad)
//  B  hist1 (float4 uv reads) -> aux1[bin][blk]
//  C1 colscan (1 wave/bin, shfl scan)   C2 binscan -> start[bin]
//  D  scatter1: LDS cursors, write rec8 sorted
//  E  sample rec8 linearly -> rec4 = lo14<<16 | fp16(val), coalesced
//  F  per-segment: wave-parallel run copy -> 32KB fp16 LDS -> float4 out

#define NBINS 512   // 32 x 16 uv tiles
#define NBLK  512   // sort blocks == output segments
#define CHUNK 16384 // n / NBLK == SEGSZ
#define SEGSZ 16384
#define SBLK  2048  // sample blocks
#define SCHUNK 4096 // records per sample block
#define Q25   33554432.0f
#define IQ25  (1.0f / 33554432.0f)

__device__ __forceinline__ int bin_key2(float px, float py) {
    int kx = min(31, max(0, (int)(px * 32.0f)));
    int ky = min(15, max(0, (int)(py * 16.0f)));
    return (ky << 5) | kx;
}

// ---------------- A: repack (float4 in, 4x half2 = uint4 out) ---------------
__global__ __launch_bounds__(256) void repack4_kernel(
    const float* __restrict__ src, __half2* __restrict__ dst, int S, int logS) {
    int t = blockIdx.x * blockDim.x + threadIdx.x;
    int idx = t * 4;
    int N = S << logS;
    if (idx >= N) return;
    int y = idx >> logS;
    float4 a = *(const float4*)(src + idx);
    float4 b = *(const float4*)(src + ((y < S - 1) ? idx + S : idx));
    __half2 q[4];
    q[0] = __halves2half2(__float2half(a.x), __float2half(b.x));
    q[1] = __halves2half2(__float2half(a.y), __float2half(b.y));
    q[2] = __halves2half2(__float2half(a.z), __float2half(b.z));
    q[3] = __halves2half2(__float2half(a.w), __float2half(b.w));
    *(uint4*)(dst + idx) = *(const uint4*)q;
}

// ---------------- B: histogram ---------------------------------------------
__global__ __launch_bounds__(256) void hist1_kernel(
    const float2* __restrict__ uv, unsigned* __restrict__ aux1) {
    __shared__ unsigned h[NBINS];
    for (int j = threadIdx.x; j < NBINS; j += 256) h[j] = 0;
    __syncthreads();
    const float4* uv4 = (const float4*)(uv + (size_t)blockIdx.x * CHUNK);
    for (int i = threadIdx.x; i < CHUNK / 2; i += 256) {
        float4 q = uv4[i];
        atomicAdd(&h[bin_key2(q.x, q.y)], 1u);
        atomicAdd(&h[bin_key2(q.z, q.w)], 1u);
    }
    __syncthreads();
    for (int j = threadIdx.x; j < NBINS; j += 256)
        aux1[j * NBLK + blockIdx.x] = h[j];
}

// ---------------- C1: per-bin scan across blocks (1 wave/bin) ---------------
__global__ __launch_bounds__(256) void colscan_kernel(
    unsigned* __restrict__ aux1, unsigned* __restrict__ total) {
    int bin = blockIdx.x * 4 + (threadIdx.x >> 6);  // grid = NBINS/4
    int lane = threadIdx.x & 63;
    unsigned* row = aux1 + (size_t)bin * NBLK;
    unsigned carry = 0;
    for (int c = 0; c < NBLK; c += 64) {
        unsigned v = row[c + lane];
        unsigned x = v;
        for (int off = 1; off < 64; off <<= 1) {
            unsigned u = __shfl_up(x, off, 64);
            if (lane >= off) x += u;
        }
        row[c + lane] = carry + x - v;  // exclusive
        carry += __shfl(x, 63, 64);
    }
    if (lane == 0) total[bin] = carry;
}

// ---------------- C2: scan of totals ---------------------------------------
__global__ __launch_bounds__(512) void binscan_kernel(
    const unsigned* __restrict__ total, unsigned* __restrict__ start) {
    __shared__ unsigned s[NBINS];
    int t = threadIdx.x;  // 512
    unsigned v = total[t];
    s[t] = v;
    __syncthreads();
    for (int off = 1; off < NBINS; off <<= 1) {
        unsigned x = (t >= off) ? s[t - off] : 0;
        __syncthreads();
        s[t] += x;
        __syncthreads();
    }
    start[t] = s[t] - v;  // exclusive
}

// ---------------- D: scatter 8B records ------------------------------------
__device__ __forceinline__ void scat_one(float px, float py, unsigned lo,
                                         unsigned* cur, uint2* __restrict__ rec8) {
    unsigned qu = min((unsigned)(px * Q25 + 0.5f), (unsigned)(Q25 - 1.0f));
    unsigned qv = min((unsigned)(py * Q25 + 0.5f), (unsigned)(Q25 - 1.0f));
    unsigned long long r = (unsigned long long)qu |
                           ((unsigned long long)qv << 25) |
                           ((unsigned long long)lo << 50);
    unsigned pos = atomicAdd(&cur[bin_key2(px, py)], 1u);
    rec8[pos] = make_uint2((unsigned)r, (unsigned)(r >> 32));
}

__global__ __launch_bounds__(256) void scatter1_kernel(
    const float2* __restrict__ uv, const unsigned* __restrict__ aux1,
    const unsigned* __restrict__ start, uint2* __restrict__ rec8) {
    __shared__ unsigned cur[NBINS];
    int g = blockIdx.x;
    for (int j = threadIdx.x; j < NBINS; j += 256)
        cur[j] = start[j] + aux1[j * NBLK + g];
    __syncthreads();
    const float4* uv4 = (const float4*)(uv + (size_t)g * CHUNK);
    for (int i = threadIdx.x; i < CHUNK / 2; i += 256) {
        float4 q = uv4[i];
        scat_one(q.x, q.y, 2 * i, cur, rec8);      // lo = idx & 16383 = 2i
        scat_one(q.z, q.w, 2 * i + 1, cur, rec8);
    }
}

// ---------------- sampling core (validated: absmax 0.031) -------------------
__device__ __forceinline__ float sample_level(const __half2* __restrict__ R,
                                              const int S, const float gx,
                                              const float gy) {
    const float halfS = 0.5f * (float)S;
    float x = (gx + 1.0f) * halfS - 0.5f;
    float y = (gy + 1.0f) * halfS - 0.5f;
    float xf = floorf(x), yf = floorf(y);
    float wx = x - xf, wy = y - yf;
    int x0 = (int)xf, y0 = (int)yf;

    int yc = min(max(y0, 0), S - 1);
    float wa = (y0 >= 0) ? (1.0f - wy) : wy;
    if (y0 < -1 || y0 >= S) wa = 0.0f;
    float wb = (y0 >= 0 && y0 < S - 1) ? wy : 0.0f;

    int xb = min(max(x0, 0), S - 2);
    bool xin = (x0 >= 0) && (x0 <= S - 2);
    float wxa = xin ? (1.0f - wx) : ((x0 == -1) ? wx : 0.0f);
    float wxb = xin ? wx : ((x0 == S - 1) ? (1.0f - wx) : 0.0f);

    uint2 q;
    __builtin_memcpy(&q, (const char*)(R + (size_t)yc * (size_t)S + xb), 8);
    __half2 ca = *(const __half2*)&q.x;
    __half2 cb = *(const __half2*)&q.y;
    float2 fa = __half22float2(ca);
    float2 fb = __half22float2(cb);
    float cola = fmaf(wa, fa.x, wb * fa.y);
    float colb = fmaf(wa, fb.x, wb * fb.y);
    return fmaf(wxa, cola, wxb * colb);
}

__device__ __forceinline__ float sample_all(const __half2* r1, const __half2* r2,
                                            const __half2* r3, const __half2* r4,
                                            float2 p) {
    float gx = p.x * 2.0f - 1.0f;
    float gy = p.y * 2.0f - 1.0f;
    float acc = sample_level(r1, 2048, gx, gy);
    acc += sample_level(r2, 1024, gx, gy);
    acc += sample_level(r3, 512, gx, gy);
    acc += sample_level(r4, 256, gx, gy);
    return acc;
}

// ---------------- E: sample linearly, packed record out ---------------------
__global__ __launch_bounds__(256) void sample_lin_kernel(
    const uint2* __restrict__ rec8, const __half2* __restrict__ r1,
    const __half2* __restrict__ r2, const __half2* __restrict__ r3,
    const __half2* __restrict__ r4, unsigned* __restrict__ rec4) {
    int base = blockIdx.x * SCHUNK;
    for (int k = base + threadIdx.x; k < base + SCHUNK; k += 256) {
        uint2 rv = rec8[k];
        unsigned long long r =
            (unsigned long long)rv.x | ((unsigned long long)rv.y << 32);
        float2 p;
        p.x = (float)(unsigned)(r & 0x1FFFFFFu) * IQ25;
        p.y = (float)(unsigned)((r >> 25) & 0x1FFFFFFu) * IQ25;
        unsigned lo = (unsigned)(r >> 50);
        float acc = sample_all(r1, r2, r3, r4, p);
        unsigned short hv = __half_as_ushort(__float2half(acc));
        rec4[k] = (lo << 16) | (unsigned)hv;
    }
}

// ---------------- F: per-segment wave-parallel run copy -> out --------------
__global__ __launch_bounds__(256) void final_kernel(
    const unsigned* __restrict__ rec4, const unsigned* __restrict__ aux1,
    const unsigned* __restrict__ start, const unsigned* __restrict__ total,
    float* __restrict__ out) {
    __shared__ unsigned rb[NBINS];
    __shared__ unsigned rl[NBINS];
    __shared__ unsigned short obuf[SEGSZ];  // 32 KB; every slot written once
    int s = blockIdx.x;
    for (int k = threadIdx.x; k < NBINS; k += 256) {
        unsigned b0 = start[k] + aux1[(size_t)k * NBLK + s];
        unsigned b1 =
            start[k] + ((s < NBLK - 1) ? aux1[(size_t)k * NBLK + s + 1] : total[k]);
        rb[k] = b0;
        rl[k] = b1 - b0;
    }
    __syncthreads();
    int wave = threadIdx.x >> 6;  // 4 waves
    int lane = threadIdx.x & 63;
    for (int r = wave * (NBINS / 4); r < (wave + 1) * (NBINS / 4); ++r) {
        unsigned b0 = rb[r], len = rl[r];
        for (unsigned off = lane; off < len; off += 64) {
            unsigned rv = rec4[b0 + off];
            obuf[rv >> 16] = (unsigned short)(rv & 0xFFFFu);
        }
    }
    __syncthreads();
    float4* o4 = (float4*)(out + (size_t)s * SEGSZ);
    for (int j = threadIdx.x; j < SEGSZ / 4; j += 256)
        o4[j] = make_float4(__half2float(__ushort_as_half(obuf[4 * j])),
                            __half2float(__ushort_as_half(obuf[4 * j + 1])),
                            __half2float(__ushort_as_half(obuf[4 * j + 2])),
                            __half2float(__ushort_as_half(obuf[4 * j + 3])));
}

// ---------------- fallbacks -------------------------------------------------
__global__ __launch_bounds__(256) void lappyr_sample_kernel(
    const float2* __restrict__ uv, const __half2* __restrict__ r1,
    const __half2* __restrict__ r2, const __half2* __restrict__ r3,
    const __half2* __restrict__ r4, float* __restrict__ out, int n) {
    int i = blockIdx.x * blockDim.x + threadIdx.x;
    if (i >= n) return;
    out[i] = sample_all(r1, r2, r3, r4, uv[i]);
}

__device__ __forceinline__ float bilin_f32(const float* __restrict__ img,
                                           const int S, const float gx,
                                           const float gy) {
    const float halfS = 0.5f * (float)S;
    float x = (gx + 1.0f) * halfS - 0.5f;
    float y = (gy + 1.0f) * halfS - 0.5f;
    float xf = floorf(x), yf = floorf(y);
    float wx = x - xf, wy = y - yf;
    int x0 = (int)xf, y0 = (int)yf, x1 = x0 + 1, y1 = y0 + 1;
    float ex0 = (x0 >= 0 && x0 < S) ? (1.0f - wx) : 0.0f;
    float ex1 = (x1 >= 0 && x1 < S) ? wx : 0.0f;
    float ey0 = (y0 >= 0 && y0 < S) ? (1.0f - wy) : 0.0f;
    float ey1 = (y1 >= 0 && y1 < S) ? wy : 0.0f;
    int xc0 = min(max(x0, 0), S - 1), xc1 = min(max(x1, 0), S - 1);
    int yc0 = min(max(y0, 0), S - 1), yc1 = min(max(y1, 0), S - 1);
    const float* r0 = img + (size_t)yc0 * S;
    const float* r1 = img + (size_t)yc1 * S;
    return ey0 * fmaf(ex0, r0[xc0], ex1 * r0[xc1]) +
           ey1 * fmaf(ex0, r1[xc0], ex1 * r1[xc1]);
}

__global__ __launch_bounds__(256) void lappyr_f32_kernel(
    const float2* __restrict__ uv, const float* __restrict__ l1,
    const float* __restrict__ l2, const float* __restrict__ l3,
    const float* __restrict__ l4, float* __restrict__ out, int n) {
    int i = blockIdx.x * blockDim.x + threadIdx.x;
    if (i >= n) return;
    float2 p = uv[i];
    float gx = p.x * 2.0f - 1.0f;
    float gy = p.y * 2.0f - 1.0f;
    float acc = bilin_f32(l1, 2048, gx, gy);
    acc += bilin_f32(l2, 1024, gx, gy);
    acc += bilin_f32(l3, 512, gx, gy);
    acc += bilin_f32(l4, 256, gx, gy);
    out[i] = acc;
}

// ---------------- launch ----------------------------------------------------
extern "C" void kernel_launch(void* const* d_in, const int* in_sizes, int n_in,
                              void* d_out, int out_size, void* d_ws, size_t ws_size,
                              hipStream_t stream) {
    const float2* uv = (const float2*)d_in[0];
    const float* l1 = (const float*)d_in[1];
    const float* l2 = (const float*)d_in[2];
    const float* l3 = (const float*)d_in[3];
    const float* l4 = (const float*)d_in[4];
    float* out = (float*)d_out;
    int n = out_size;  // 8*1024*1024 = NBLK*CHUNK = SBLK*SCHUNK

    const size_t n1 = 2048u * 2048u, n2 = 1024u * 1024u, n3 = 512u * 512u,
                 n4 = 256u * 256u;
    const size_t repack_bytes = (n1 + n2 + n3 + n4) * 4;  // 21.25 MiB
    const size_t aux1_bytes = (size_t)NBINS * NBLK * 4;   // 1 MiB
    const size_t tot_bytes = NBINS * 4, start_bytes = NBINS * 4;
    const size_t rec8_bytes = (size_t)n * 8;              // 64 MiB
    const size_t rec4_bytes = (size_t)n * 4;              // 32 MiB
    const size_t need = repack_bytes + aux1_bytes + tot_bytes + start_bytes +
                        rec8_bytes + rec4_bytes;          // ~118.3 MiB

    if (n == NBLK * CHUNK && ws_size >= need) {
        char* base = (char*)d_ws;
        __half2* r1 = (__half2*)base;
        __half2* r2 = r1 + n1;
        __half2* r3 = r2 + n2;
        __half2* r4 = r3 + n3;
        char* p = base + repack_bytes;
        unsigned* aux1 = (unsigned*)p;   p += aux1_bytes;
        unsigned* total = (unsigned*)p;  p += tot_bytes;
        unsigned* start = (unsigned*)p;  p += start_bytes;
        uint2* rec8 = (uint2*)p;         p += rec8_bytes;
        unsigned* rec4 = (unsigned*)p;

        repack4_kernel<<<(int)(n1 / 4 / 256), 256, 0, stream>>>(l1, r1, 2048, 11);
        repack4_kernel<<<(int)(n2 / 4 / 256), 256, 0, stream>>>(l2, r2, 1024, 10);
        repack4_kernel<<<(int)(n3 / 4 / 256), 256, 0, stream>>>(l3, r3, 512, 9);
        repack4_kernel<<<(int)(n4 / 4 / 256), 256, 0, stream>>>(l4, r4, 256, 8);
        hist1_kernel<<<NBLK, 256, 0, stream>>>(uv, aux1);
        colscan_kernel<<<NBINS / 4, 256, 0, stream>>>(aux1, total);
        binscan_kernel<<<1, NBINS, 0, stream>>>(total, start);
        scatter1_kernel<<<NBLK, 256, 0, stream>>>(uv, aux1, start, rec8);
        sample_lin_kernel<<<SBLK, 256, 0, stream>>>(rec8, r1, r2, r3, r4, rec4);
        final_kernel<<<NBLK, 256, 0, stream>>>(rec4, aux1, start, total, out);
    } else if (ws_size >= repack_bytes) {
        __half2* r1 = (__half2*)d_ws;
        __half2* r2 = r1 + n1;
        __half2* r3 = r2 + n2;
        __half2* r4 = r3 + n3;
        repack4_kernel<<<(int)(n1 / 4 / 256), 256, 0, stream>>>(l1, r1, 2048, 11);
        repack4_kernel<<<(int)(n2 / 4 / 256), 256, 0, stream>>>(l2, r2, 1024, 10);
        repack4_kernel<<<(int)(n3 / 4 / 256), 256, 0, stream>>>(l3, r3, 512, 9);
        repack4_kernel<<<(int)(n4 / 4 / 256), 256, 0, stream>>>(l4, r4, 256, 8);
        lappyr_sample_kernel<<<(n + 255) / 256, 256, 0, stream>>>(uv, r1, r2, r3,
                                                                  r4, out, n);
    } else {
        lappyr_f32_kernel<<<(n + 255) / 256, 256, 0, stream>>>(uv, l1, l2, l3, l4,
                                                               out, n);
    }
}